// Round 1
// baseline (594.533 us; speedup 1.0000x reference)
//
#include <hip/hip_runtime.h>
#include <stdint.h>

// Problem constants
#define NB   512      // batch
#define NL   128      // cycles per sample (GEMM M)
#define NK   900      // 3*F (GEMM K)
#define NKP  928      // K padded to 29*32
#define NKT  29       // K tiles of 32
#define ND   512      // D_MODEL (GEMM N)
#define NDLLM 4096
#define NE   8

typedef __bf16 bf16x8 __attribute__((ext_vector_type(8)));
typedef float  f32x4  __attribute__((ext_vector_type(4)));

// f32 -> bf16 bits, round-to-nearest-even (inputs are finite)
__device__ __forceinline__ unsigned short f2bf(float f) {
  union { float f; uint32_t u; } v; v.f = f;
  uint32_t u = v.u;
  return (unsigned short)((u + 0x7fffu + ((u >> 16) & 1u)) >> 16);
}

// ---------------------------------------------------------------------------
// Kernel 1: gate logits + argmax.  logits[b,e] = DKP[b,:] @ W_gate[:,e] + b_gate[e]
// Top-p with P=0.25,E=8 provably selects exactly argmax with weight exactly 1.0.
// ---------------------------------------------------------------------------
__global__ __launch_bounds__(256) void gate_kernel(
    const float* __restrict__ dkp,    // [NB, 4096]
    const float* __restrict__ Wg,     // [4096, 8]
    const float* __restrict__ bg,     // [8]
    int* __restrict__ eidx)           // [NB]
{
  const int b = blockIdx.x;
  const int t = threadIdx.x;
  float acc[8];
#pragma unroll
  for (int e = 0; e < 8; ++e) acc[e] = 0.f;
  const float* drow = dkp + (size_t)b * NDLLM;
  for (int k = t; k < NDLLM; k += 256) {
    float d = drow[k];
    const float4* w4 = (const float4*)(Wg + (size_t)k * 8);
    float4 w0 = w4[0], w1 = w4[1];
    acc[0] += d * w0.x; acc[1] += d * w0.y; acc[2] += d * w0.z; acc[3] += d * w0.w;
    acc[4] += d * w1.x; acc[5] += d * w1.y; acc[6] += d * w1.z; acc[7] += d * w1.w;
  }
#pragma unroll
  for (int e = 0; e < 8; ++e)
    for (int off = 32; off >= 1; off >>= 1)
      acc[e] += __shfl_down(acc[e], off, 64);

  __shared__ float red[4][8];
  const int wave = t >> 6, lane = t & 63;
  if (lane == 0) {
#pragma unroll
    for (int e = 0; e < 8; ++e) red[wave][e] = acc[e];
  }
  __syncthreads();
  if (t == 0) {
    float best = -1e30f; int bi = 0;
#pragma unroll
    for (int e = 0; e < 8; ++e) {
      float v = red[0][e] + red[1][e] + red[2][e] + red[3][e] + bg[e];
      if (v > best) { best = v; bi = e; }  // strict > matches stable argsort tie-break
    }
    eidx[b] = bi;
  }
}

// ---------------------------------------------------------------------------
// Kernel 2: pack W_tot[e] = W_exp[e] + W_gen[0] + W_gen[1], transposed to
// B^T layout [e][n(512)][k(928)] as bf16 bits, K zero-padded 900->928.
// ---------------------------------------------------------------------------
__global__ __launch_bounds__(256) void pack_kernel(
    const float* __restrict__ Wexp,   // [8, 900, 512]
    const float* __restrict__ Wgen,   // [2, 900, 512]
    unsigned short* __restrict__ Wt)  // [8, 512, 928] bf16 bits
{
  const int nt = blockIdx.x;          // 8 tiles of 64 n
  const int kt = blockIdx.y;          // 29 tiles of 32 k
  const int e  = blockIdx.z;
  const int k0 = kt * 32, n0 = nt * 64;
  __shared__ float tile[32][65];
  const int t = threadIdx.x;
#pragma unroll
  for (int i = 0; i < 8; ++i) {
    int idx = t + i * 256;
    int k = idx >> 6, n = idx & 63;
    int kg = k0 + k;
    float v = 0.f;
    if (kg < NK) {
      size_t off = (size_t)kg * ND + n0 + n;
      v = Wexp[(size_t)e * NK * ND + off] + Wgen[off] + Wgen[(size_t)NK * ND + off];
    }
    tile[k][n] = v;
  }
  __syncthreads();
#pragma unroll
  for (int i = 0; i < 8; ++i) {
    int idx = t + i * 256;
    int n = idx >> 5, k = idx & 31;
    Wt[((size_t)e * ND + n0 + n) * NKP + k0 + k] = f2bf(tile[k][n]);
  }
}

// ---------------------------------------------------------------------------
// Kernel 3: btot[e][d] = b_exp[e][d] + b_gen[0][d] + b_gen[1][d]
// ---------------------------------------------------------------------------
__global__ __launch_bounds__(256) void bias_kernel(
    const float* __restrict__ bexp, const float* __restrict__ bgen,
    float* __restrict__ btot)
{
  int i = blockIdx.x * 256 + threadIdx.x;   // 8*512 = 4096
  int d = i & (ND - 1);
  btot[i] = bexp[i] + bgen[d] + bgen[ND + d];
}

// ---------------------------------------------------------------------------
// Kernel 4: per-batch expert GEMM.  C[b](128x512) = X[b](128x900) @ Wt[e*[b]]
// Tile 128(M) x 128(N), K-step 32, 4 waves, 16x16x32 bf16 MFMA (m97 structure).
// A: f32 global -> cvt bf16 -> LDS [l][k].  B: bf16 global_load_lds -> LDS [n][k].
// ---------------------------------------------------------------------------
__global__ __launch_bounds__(256) void gemm_kernel(
    const float* __restrict__ x,              // [NB, NL, NK]
    const unsigned short* __restrict__ Wt,    // [8, 512, 928] bf16 bits
    const float* __restrict__ btot,           // [8, 512]
    const int* __restrict__ eidx,             // [NB]
    float* __restrict__ out)                  // [NB, NL, ND] f32
{
  __shared__ unsigned short As[NL * 32];      // [l][k] 8 KB
  __shared__ unsigned short Bs[128 * 32];     // [n][k] 8 KB

  const int b  = blockIdx.y;
  const int nt = blockIdx.x;
  const int t  = threadIdx.x;
  const int lane = t & 63;
  const int w  = t >> 6;
  const int wm = (w >> 1) * 64;               // wave row base
  const int wn = (w & 1) * 64;                // wave col base
  const int ln = lane & 15;
  const int kq = lane >> 4;

  const int e = eidx[b];
  const float* xb = x + (size_t)b * NL * NK;
  const unsigned short* wtb = Wt + ((size_t)e * ND + (size_t)nt * 128) * NKP;

  f32x4 acc[4][4];
  const f32x4 zero = {0.f, 0.f, 0.f, 0.f};
#pragma unroll
  for (int i = 0; i < 4; ++i)
#pragma unroll
    for (int j = 0; j < 4; ++j) acc[i][j] = zero;

  const int al  = t >> 3;   // A-staging base row (rows advance by 32 per pass)
  const int akc = t & 7;    // A-staging 4-float chunk within the 32-wide k tile

  for (int kt = 0; kt < NKT; ++kt) {
    const int k0 = kt * 32;
    __syncthreads();        // previous iteration's ds_reads complete

    // ---- stage B: 8 KB via global_load_lds width-16 (dest = linear lane*16) ----
#pragma unroll
    for (int p = 0; p < 2; ++p) {
      int c = t + p * 256;                  // 512 chunks of 16 B
      int n = c >> 2, kc8 = c & 3;
      const unsigned short* src = wtb + (size_t)n * NKP + k0 + kc8 * 8;
      unsigned short* dst = &Bs[c * 8];
      __builtin_amdgcn_global_load_lds(
          (__attribute__((address_space(1))) void*)(void*)src,
          (__attribute__((address_space(3))) void*)dst, 16, 0, 0);
    }

    // ---- stage A: 16 KB f32 -> 8 KB bf16, chunks fully valid or fully pad ----
#pragma unroll
    for (int p = 0; p < 4; ++p) {
      int l  = al + p * 32;
      int kg = k0 + akc * 4;
      ushort4 h;
      if (kg < NK) {
        const float4 v = *(const float4*)(xb + (size_t)l * NK + kg);
        h.x = f2bf(v.x); h.y = f2bf(v.y); h.z = f2bf(v.z); h.w = f2bf(v.w);
      } else {
        h.x = 0; h.y = 0; h.z = 0; h.w = 0;
      }
      *(ushort4*)&As[l * 32 + akc * 4] = h;
    }
    __syncthreads();        // staging (vmcnt+lgkmcnt) drained

    // ---- compute: 8 ds_read_b128 + 16 MFMA per wave ----
    bf16x8 af[4], bv[4];
#pragma unroll
    for (int mi = 0; mi < 4; ++mi)
      af[mi] = *(bf16x8*)&As[(wm + mi * 16 + ln) * 32 + kq * 8];
#pragma unroll
    for (int ni = 0; ni < 4; ++ni)
      bv[ni] = *(bf16x8*)&Bs[(wn + ni * 16 + ln) * 32 + kq * 8];
#pragma unroll
    for (int mi = 0; mi < 4; ++mi)
#pragma unroll
      for (int ni = 0; ni < 4; ++ni)
        acc[mi][ni] = __builtin_amdgcn_mfma_f32_16x16x32_bf16(
            af[mi], bv[ni], acc[mi][ni], 0, 0, 0);
  }

  // ---- epilogue: C/D layout col=lane&15, row=(lane>>4)*4+reg ----
  const float* bt = btot + (size_t)e * ND;
  const int nb = nt * 128;
#pragma unroll
  for (int ni = 0; ni < 4; ++ni) {
    int ncol = nb + wn + ni * 16 + ln;
    float bias = bt[ncol];
#pragma unroll
    for (int mi = 0; mi < 4; ++mi) {
      int l0 = wm + mi * 16 + kq * 4;
      float* op = out + ((size_t)b * NL + l0) * ND + ncol;
#pragma unroll
      for (int r = 0; r < 4; ++r)
        op[(size_t)r * ND] = acc[mi][ni][r] + bias;
    }
  }
}

// ---------------------------------------------------------------------------
// Workspace layout: [0,2048) eidx int[512] | [2048,18432) btot f32[8*512]
//                   [18432, +7602176) Wt bf16[8*512*928]   (~7.27 MiB total)
// ---------------------------------------------------------------------------
extern "C" void kernel_launch(void* const* d_in, const int* in_sizes, int n_in,
                              void* d_out, int out_size, void* d_ws, size_t ws_size,
                              hipStream_t stream) {
  const float* x     = (const float*)d_in[0];  // [512,128,3,300]
  const float* dkp   = (const float*)d_in[1];  // [512,4096]
  const float* Wexp  = (const float*)d_in[2];  // [8,900,512]
  const float* bexp  = (const float*)d_in[3];  // [8,512]
  const float* Wgen  = (const float*)d_in[4];  // [2,900,512]
  const float* bgen  = (const float*)d_in[5];  // [2,512]
  const float* Wgate = (const float*)d_in[6];  // [4096,8]
  const float* bgate = (const float*)d_in[7];  // [8]
  float* out = (float*)d_out;                  // [512,128,512] f32

  int*   eidx = (int*)d_ws;
  float* btot = (float*)((char*)d_ws + 2048);
  unsigned short* Wt = (unsigned short*)((char*)d_ws + 18432);

  gate_kernel<<<NB, 256, 0, stream>>>(dkp, Wgate, bgate, eidx);
  pack_kernel<<<dim3(8, NKT, NE), 256, 0, stream>>>(Wexp, Wgen, Wt);
  bias_kernel<<<16, 256, 0, stream>>>(bexp, bgen, btot);
  gemm_kernel<<<dim3(4, NB), 256, 0, stream>>>(x, Wt, btot, eidx, out);
}